// Round 6
// baseline (223.674 us; speedup 1.0000x reference)
//
#include <hip/hip_runtime.h>

// MV_GCN on MI355X — round 8: kill the LDS-broadcast bottleneck.
// r1/r5 evidence: GEMM phases read A via wave-uniform broadcast ds_read_b128;
// a broadcast still delivers 1024 B to VGPRs (~12 cyc on the per-CU LDS pipe)
// -> ~74 µs/CU of LDS serialization, which is why occupancy 33->77% changed
// nothing (VALUBusy pinned at ~39%).
// New mapping: lane = output row (64 rows + 52 in slot2), wave = 8 output
// columns. A is read PER-LANE (one b128 covers 64 distinct rows, stride 116
// words = 29*16B -> chunk group 29*l mod 8, gcd=1, conflict-free), 4x fewer
// LDS instructions at full bandwidth. Streamed operand (X/W rows, 8 contiguous
// cols) is wave-uniform via readfirstlane -> s_load + SGPR-operand v_fmac.
// __launch_bounds__ arg2 deduced = min BLOCKS/CU ((512,4)->64, (512,8)->32,
// (1024,4)->32 VGPR observed): use (1024,2) -> cap 64 VGPR, 2 blocks/CU.

#define NB 256
#define NODES 116
#define FEAT 115
#define LENN 6670
#define SEG2 13456
#define HID 128
#define HC 512
#define ASTR 116   // row stride in words; 464 B = 29*16 -> 16B-aligned rows

__global__ __launch_bounds__(1024, 2) void k_fused(
    const float* __restrict__ x, const int* __restrict__ ei,
    const float* __restrict__ ew,
    const float* __restrict__ W1, const float* __restrict__ b1,
    const float* __restrict__ W2, const float* __restrict__ b2,
    float* __restrict__ featws)
{
  __shared__ __align__(16) float sA[NODES * ASTR];   // A_hat, then M = A_hat@X
  __shared__ float dinv[NODES];
  __shared__ float pmax[16 * 128];                   // per-wave column maxima
  const int bid = blockIdx.x;
  const int g = bid >> 1, v = bid & 1;
  const int tid = threadIdx.x;

  // ---- phase 0: zero A (116*116 = 13456 f32 = 3364 float4, exact)
  const float4 z4 = make_float4(0.f, 0.f, 0.f, 0.f);
  for (int i = tid; i < (NODES * ASTR) / 4; i += 1024) ((float4*)sA)[i] = z4;
  __syncthreads();

  // ---- phase 1: single edge scan: A_raw[d][s] += w (deg = row sums later)
  const int eoff = g * SEG2 + v * LENN;
  const int nbase = g * 232 + v * 116;
  const int* __restrict__ srcp = ei + eoff;
  const int* __restrict__ dstp = ei + (size_t)NB * SEG2 + eoff;
  const float* __restrict__ wp = ew + eoff;
#pragma unroll 2
  for (int q = tid; q < (LENN / 2); q += 1024) {
    int2 s2 = ((const int2*)srcp)[q];
    int2 d2 = ((const int2*)dstp)[q];
    float2 w2 = ((const float2*)wp)[q];
    atomicAdd(&sA[(d2.x - nbase) * ASTR + (s2.x - nbase)], w2.x);
    atomicAdd(&sA[(d2.y - nbase) * ASTR + (s2.y - nbase)], w2.y);
  }
  __syncthreads();

  // ---- phase 2: deg via row sums (4 threads/row, stride-29 starts)
  if (tid < 4 * NODES) {
    const int r = tid >> 2, q = tid & 3;
    const float* row = &sA[r * ASTR + q * 29];
    float s = 0.f;
#pragma unroll
    for (int j = 0; j < 29; ++j) s += row[j];
    s += __shfl_xor(s, 1, 64);
    s += __shfl_xor(s, 2, 64);
    if (q == 0) dinv[r] = rsqrtf(s + 1.0f);   // deg + 1 self-loop
  }
  __syncthreads();

  // ---- phase 3: normalize in place; fold self-loop dinv^2 into diagonal
  // (ASTR == NODES so linear idx == matrix addr)
  for (int idx = tid; idx < NODES * NODES; idx += 1024) {
    int d = idx / NODES;
    int s = idx - d * NODES;
    float di = dinv[d];
    float val = sA[idx] * (di * dinv[s]);
    if (d == s) val += di * di;
    sA[idx] = val;
  }
  __syncthreads();

  // ---- GEMM decomposition: lane = row, wave = 8 contiguous output columns
  const int lane = tid & 63;
  const int wid  = tid >> 6;                               // 0..15
  const int c0u  = __builtin_amdgcn_readfirstlane(wid << 3);  // uniform col base
  const int r0 = lane;
  const int r1 = (lane + 64 < NODES) ? (lane + 64) : (NODES - 1); // dup rows benign
  const float* __restrict__ A0 = &sA[r0 * ASTR];
  const float* __restrict__ A1 = &sA[r1 * ASTR];

  // ---- phase 4: M = A_hat @ X ; valid output cols are 0..114
  const float* __restrict__ Xu = x + (size_t)nbase * FEAT;  // uniform base
  float acc0[8], acc1[8];
#pragma unroll
  for (int j = 0; j < 8; ++j) { acc0[j] = 0.f; acc1[j] = 0.f; }

  float4 a0n = *(const float4*)(A0);
  float4 a1n = *(const float4*)(A1);
  for (int kb = 0; kb < 29; ++kb) {          // K = 116 = 29*4 exact
    const int k0 = kb * 4;
    float ar0[4], ar1[4];
    ar0[0] = a0n.x; ar0[1] = a0n.y; ar0[2] = a0n.z; ar0[3] = a0n.w;
    ar1[0] = a1n.x; ar1[1] = a1n.y; ar1[2] = a1n.z; ar1[3] = a1n.w;
    if (kb < 28) {                           // prefetch next 4 K of A rows
      a0n = *(const float4*)(A0 + k0 + 4);
      a1n = *(const float4*)(A1 + k0 + 4);
    }
#pragma unroll
    for (int kk = 0; kk < 4; ++kk) {
      const float* __restrict__ xrow = Xu + (size_t)(k0 + kk) * FEAT;
      float xv[8];
#pragma unroll
      for (int j = 0; j < 8; ++j) {          // uniform: s_load + SGPR operand
        const int c = c0u + j;
        const int cc = (c < FEAT) ? c : (FEAT - 1);   // clamp addr (no OOB)
        const float xl = xrow[cc];
        xv[j] = (c < FEAT) ? xl : 0.f;                // mask invalid cols
      }
#pragma unroll
      for (int j = 0; j < 8; ++j) {
        acc0[j] = fmaf(ar0[kk], xv[j], acc0[j]);
        acc1[j] = fmaf(ar1[kk], xv[j], acc1[j]);
      }
    }
  }
  __syncthreads();   // everyone done reading A_hat

  // ---- phase 5: M overwrites sA; col 115 stores 0 (masked accs), cols>=116 skipped
  if (c0u + 3 < NODES) {     // waves 0..14: cols c0u..c0u+3
    *(float4*)&sA[r0 * ASTR + c0u] = make_float4(acc0[0], acc0[1], acc0[2], acc0[3]);
    *(float4*)&sA[r1 * ASTR + c0u] = make_float4(acc1[0], acc1[1], acc1[2], acc1[3]);
  }
  if (c0u + 7 < NODES) {     // waves 0..13: cols c0u+4..c0u+7
    *(float4*)&sA[r0 * ASTR + c0u + 4] = make_float4(acc0[4], acc0[5], acc0[6], acc0[7]);
    *(float4*)&sA[r1 * ASTR + c0u + 4] = make_float4(acc1[4], acc1[5], acc1[6], acc1[7]);
  }
  __syncthreads();

  // ---- phase 6: out = M @ W + b ; 128 cols = 16 waves * 8 exact
  const float* __restrict__ W  = v ? W2 : W1;
  const float* __restrict__ bv = v ? b2 : b1;
#pragma unroll
  for (int j = 0; j < 8; ++j) {
    const float bj = bv[c0u + j];            // uniform
    acc0[j] = bj; acc1[j] = bj;
  }

  a0n = *(const float4*)(A0);
  a1n = *(const float4*)(A1);
  for (int kb = 0; kb < 29; ++kb) {          // K = 116; M[.][115]=0 kills k=115
    const int k0 = kb * 4;
    float ar0[4], ar1[4];
    ar0[0] = a0n.x; ar0[1] = a0n.y; ar0[2] = a0n.z; ar0[3] = a0n.w;
    ar1[0] = a1n.x; ar1[1] = a1n.y; ar1[2] = a1n.z; ar1[3] = a1n.w;
    if (kb < 28) {
      a0n = *(const float4*)(A0 + k0 + 4);
      a1n = *(const float4*)(A1 + k0 + 4);
    }
#pragma unroll
    for (int kk = 0; kk < 4; ++kk) {
      const int k = k0 + kk;
      const int kc = (k < FEAT) ? k : (FEAT - 1);     // W row clamp (k=115)
      const float* __restrict__ wrow = W + (size_t)kc * HID + c0u;
      float wv[8];
#pragma unroll
      for (int j = 0; j < 8; ++j) wv[j] = wrow[j];    // uniform s_load
#pragma unroll
      for (int j = 0; j < 8; ++j) {
        acc0[j] = fmaf(ar0[kk], wv[j], acc0[j]);
        acc1[j] = fmaf(ar1[kk], wv[j], acc1[j]);
      }
    }
  }

  // ---- phase 7: channel max. Per-lane max over this wave's 8 cols, then
  // cross-wave reduce via pmax[wave][row] (stride 128: lanes hit bank l%32).
  float m0 = fmaxf(fmaxf(fmaxf(acc0[0], acc0[1]), fmaxf(acc0[2], acc0[3])),
                   fmaxf(fmaxf(acc0[4], acc0[5]), fmaxf(acc0[6], acc0[7])));
  float m1 = fmaxf(fmaxf(fmaxf(acc1[0], acc1[1]), fmaxf(acc1[2], acc1[3])),
                   fmaxf(fmaxf(acc1[4], acc1[5]), fmaxf(acc1[6], acc1[7])));
  pmax[(wid << 7) + r0] = m0;
  pmax[(wid << 7) + r1] = m1;      // dup rows write identical values: benign
  __syncthreads();
  if (tid < NODES) {
    float m = pmax[tid];
#pragma unroll
    for (int w = 1; w < 16; ++w) m = fmaxf(m, pmax[(w << 7) + tid]);
    featws[g * 232 + 2 * tid + v] = m;   // stack([x1,x2],1).reshape
  }
}

// ---------------- K2: MLP  relu(feat@W6+b6)@W7+b7 ----------------
// 1024 threads: col = tid&511, K-half = tid>>9 (116 rows each), LDS combine.
__global__ __launch_bounds__(1024) void k_mlp(
    const float* __restrict__ featws, const float* __restrict__ W6,
    const float* __restrict__ b6, const float* __restrict__ W7,
    const float* __restrict__ b7, float* __restrict__ out)
{
  __shared__ float sf[232];
  __shared__ float ph[512];
  __shared__ float red[8];
  const int g = blockIdx.x, tid = threadIdx.x;
  if (tid < 232) sf[tid] = featws[g * 232 + tid];
  __syncthreads();

  const int col = tid & 511, half = tid >> 9;
  const float* __restrict__ w6p = W6 + (size_t)(half * 116) * HC + col;
  const float* __restrict__ sfh = sf + half * 116;
  float p = 0.f;
#pragma unroll 4
  for (int k = 0; k < 116; ++k)
    p = fmaf(sfh[k], w6p[(size_t)k * HC], p);
  if (half) ph[col] = p;
  __syncthreads();

  if (!half) {
    float a = b6[col] + p + ph[col];
    a = fmaxf(a, 0.f) * W7[col];
#pragma unroll
    for (int off = 32; off >= 1; off >>= 1) a += __shfl_xor(a, off, 64);
    if ((tid & 63) == 0) red[tid >> 6] = a;
  }
  __syncthreads();
  if (tid == 0) {
    float t = b7[0];
#pragma unroll
    for (int i = 0; i < 8; ++i) t += red[i];
    out[g] = t;
  }
}

extern "C" void kernel_launch(void* const* d_in, const int* in_sizes, int n_in,
                              void* d_out, int out_size, void* d_ws, size_t ws_size,
                              hipStream_t stream)
{
  const float* x  = (const float*)d_in[0];
  const int*   ei = (const int*)d_in[1];
  const float* ew = (const float*)d_in[2];
  // d_in[3] = batch (unused by reference)
  const float* W1 = (const float*)d_in[4];
  const float* b1 = (const float*)d_in[5];
  const float* W2 = (const float*)d_in[6];
  const float* b2 = (const float*)d_in[7];
  const float* W6 = (const float*)d_in[8];
  const float* b6 = (const float*)d_in[9];
  const float* W7 = (const float*)d_in[10];
  const float* b7 = (const float*)d_in[11];

  float* featws = (float*)d_ws;                 // 256*232 f32 = 237 KB
  float* out    = (float*)d_out;

  hipLaunchKernelGGL(k_fused, dim3(2 * NB), dim3(1024), 0, stream,
                     x, ei, ew, W1, b1, W2, b2, featws);
  hipLaunchKernelGGL(k_mlp,   dim3(NB),     dim3(1024), 0, stream,
                     featws, W6, b6, W7, b7, out);
}

// Round 7
// 182.249 us; speedup vs baseline: 1.2273x; 1.2273x over previous
//
#include <hip/hip_runtime.h>

// MV_GCN on MI355X — round 9: move the GEMMs to the matrix pipe (bf16x3 MFMA).
// 6 rounds of vector-pipe scheduling all land 100-126us (>=4x the 25us FMA
// floor) with MfmaUtil=0. This round: per (g,v) block, build A_hat f32 in LDS
// (unchanged, verified), convert in-place to swizzled bf16 hi/lo, stage X^T /
// W^T as bf16 hi/lo, and run both GEMMs as 16x16x32_bf16 MFMAs with the x3
// scheme (hi*hi + lo*hi + hi*lo => ~2^-17 rel error, way under the 2.29e-3
// threshold). 1 block/CU (134 KB LDS), 16 waves, wave = 2x2 C-tiles.
// Frag k-order: two K=16 halves (k = 16*(j>>2) + 4*(lane>>4) + (j&3)),
// realized via kperm() at store time so frag reads are contiguous b128;
// XOR swizzle ((row&7)<<4) makes them 2-way bank-aliased = free.

#define NB 256
#define NODES 116
#define FEAT 115
#define LENN 6670
#define SEG2 13456
#define HID 128
#define HC 512

typedef float f32x4 __attribute__((ext_vector_type(4)));
typedef short short8 __attribute__((ext_vector_type(8)));
typedef __bf16 bf16x8 __attribute__((ext_vector_type(8)));

#define MFMA16(a, b, c) __builtin_amdgcn_mfma_f32_16x16x32_bf16( \
    __builtin_bit_cast(bf16x8, (a)), __builtin_bit_cast(bf16x8, (b)), (c), 0, 0, 0)

// LDS map (bytes):
//   [0,32768)      A_hi [128 rows][128 k] bf16, swizzled+kperm
//   [32768,65536)  A_lo                     } union: A_f32 float[128][128]
//   [65536,98304)  B_hi [128 rows][128 k]   (X^T, then W^T)
//   [98304,131072) B_lo
//   [131072,133120) pmax float[4][128]
//   [133120,133632) dinv float[128]
#define OFF_ALO 32768
#define OFF_BHI 65536
#define OFF_BLO 98304
#define OFF_PMAX 131072
#define OFF_DINV 133120
#define LDS_BYTES 133632

__device__ __forceinline__ unsigned f2bf(float f) {        // f32 -> bf16 RNE
  unsigned u = __builtin_bit_cast(unsigned, f);
  return (u + 0x7FFFu + ((u >> 16) & 1u)) >> 16;
}
__device__ __forceinline__ float bf2f(unsigned h) {
  return __builtin_bit_cast(float, h << 16);
}
__device__ __forceinline__ int kperm(int k) {  // frag k-order within 32-chunks
  return (k & ~31) | (k & 3) | (((k >> 2) & 3) << 3) | (((k >> 4) & 1) << 2);
}
__device__ __forceinline__ int swzb(int row, int kbyte) {  // bank spread
  return row * 256 + (kbyte ^ ((row & 7) << 4));
}
__device__ __forceinline__ f32x4 splat4(float f) {
  f32x4 r = {f, f, f, f};
  return r;
}

__global__ __launch_bounds__(1024, 1) void k_fused(
    const float* __restrict__ x, const int* __restrict__ ei,
    const float* __restrict__ ew,
    const float* __restrict__ W1, const float* __restrict__ b1,
    const float* __restrict__ W2, const float* __restrict__ b2,
    float* __restrict__ featws)
{
  __shared__ __align__(16) char sm[LDS_BYTES];
  float* Af = (float*)sm;
  float* dinv = (float*)(sm + OFF_DINV);
  float* pmaxp = (float*)(sm + OFF_PMAX);
  const int bid = blockIdx.x;
  const int g = bid >> 1, v = bid & 1;
  const int tid = threadIdx.x;

  // ---- P0: zero A_f32 + B regions (131072 B = 8192 float4, 8/thread exact)
  {
    f32x4 z = splat4(0.f);
    f32x4* p = (f32x4*)sm;
#pragma unroll
    for (int i = 0; i < 8; ++i) p[tid + (i << 10)] = z;
  }
  __syncthreads();

  // ---- P1: edge scatter A_f32[d][s] += w ; stage X^T as bf16 hi/lo
  const int eoff = g * SEG2 + v * LENN;
  const int nbase = g * 232 + v * 116;
  {
    const int* __restrict__ srcp = ei + eoff;
    const int* __restrict__ dstp = ei + (size_t)NB * SEG2 + eoff;
    const float* __restrict__ wp = ew + eoff;
    for (int q = tid; q < (LENN / 2); q += 1024) {
      int2 s2 = ((const int2*)srcp)[q];
      int2 d2 = ((const int2*)dstp)[q];
      float2 w2 = ((const float2*)wp)[q];
      atomicAdd(&Af[((d2.x - nbase) << 7) + (s2.x - nbase)], w2.x);
      atomicAdd(&Af[((d2.y - nbase) << 7) + (s2.y - nbase)], w2.y);
    }
    const float* __restrict__ xg = x + (size_t)nbase * FEAT;
    for (int idx = tid; idx < NODES * FEAT; idx += 1024) {
      int s = idx / FEAT;            // node  (K index of phase-A GEMM)
      int c = idx - s * FEAT;        // feat  (row of B^T = output col)
      float f = xg[idx];
      unsigned hi = f2bf(f);
      unsigned lo = f2bf(f - bf2f(hi));
      int byte = swzb(c, kperm(s) << 1);
      *(unsigned short*)(sm + OFF_BHI + byte) = (unsigned short)hi;
      *(unsigned short*)(sm + OFF_BLO + byte) = (unsigned short)lo;
    }
  }
  __syncthreads();

  // ---- P2: degree via row sums (4 threads/row, stride-29 starts)
  if (tid < 4 * NODES) {
    const int r = tid >> 2, q = tid & 3;
    const float* row = Af + (r << 7) + q * 29;
    float s = 0.f;
#pragma unroll
    for (int j = 0; j < 29; ++j) s += row[j];
    s += __shfl_xor(s, 1, 64);
    s += __shfl_xor(s, 2, 64);
    if (q == 0) dinv[r] = rsqrtf(s + 1.0f);   // deg + 1 self-loop
  }
  __syncthreads();

  // ---- P3: normalize; fold self-loop dinv^2 into diagonal
  for (int idx = tid; idx < NODES * 128; idx += 1024) {
    int d = idx >> 7, s = idx & 127;
    if (s < NODES) {
      float di = dinv[d];
      float val = Af[idx] * (di * dinv[s]);
      if (d == s) val += di * di;
      Af[idx] = val;
    }
  }
  __syncthreads();

  // ---- P4: convert A_f32 -> A_hi/A_lo in place (16 f32/thread via regs)
  {
    const int t16 = tid << 4;
    const int row = t16 >> 7;
    const int k0 = t16 & 127;
    f32x4 vv[4];
#pragma unroll
    for (int q2 = 0; q2 < 4; ++q2) vv[q2] = *(f32x4*)(Af + t16 + (q2 << 2));
    __syncthreads();                 // all reads done before any overwrite
#pragma unroll
    for (int q2 = 0; q2 < 4; ++q2)
#pragma unroll
      for (int j = 0; j < 4; ++j) {
        float f = vv[q2][j];
        unsigned hi = f2bf(f);
        unsigned lo = f2bf(f - bf2f(hi));
        int byte = swzb(row, kperm(k0 + (q2 << 2) + j) << 1);
        *(unsigned short*)(sm + byte) = (unsigned short)hi;
        *(unsigned short*)(sm + OFF_ALO + byte) = (unsigned short)lo;
      }
  }
  __syncthreads();

  // ---- MFMA geometry: wave (mg,ng) owns m-tiles 2mg..2mg+1 x n-tiles 2ng..2ng+1
  const int lane = tid & 63, w = tid >> 6;
  const int mg = w >> 2, ng = w & 3;
  const int rA0 = (mg << 5) + (lane & 15), rA1 = rA0 + 16;
  const int rB0 = (ng << 5) + (lane & 15), rB1 = rB0 + 16;
  const int kb = (lane >> 4) << 4;         // k-subgroup byte offset

  f32x4 acc00 = splat4(0.f), acc01 = splat4(0.f);
  f32x4 acc10 = splat4(0.f), acc11 = splat4(0.f);

  // ---- P5: M = A_hat @ X (bf16x3)
#pragma unroll
  for (int kc = 0; kc < 4; ++kc) {
    const int ko = (kc << 6) + kb;
    short8 a0h = *(const short8*)(sm + swzb(rA0, ko));
    short8 a0l = *(const short8*)(sm + OFF_ALO + swzb(rA0, ko));
    short8 a1h = *(const short8*)(sm + swzb(rA1, ko));
    short8 a1l = *(const short8*)(sm + OFF_ALO + swzb(rA1, ko));
    short8 b0h = *(const short8*)(sm + OFF_BHI + swzb(rB0, ko));
    short8 b0l = *(const short8*)(sm + OFF_BLO + swzb(rB0, ko));
    short8 b1h = *(const short8*)(sm + OFF_BHI + swzb(rB1, ko));
    short8 b1l = *(const short8*)(sm + OFF_BLO + swzb(rB1, ko));
    acc00 = MFMA16(a0h, b0h, acc00); acc00 = MFMA16(a0l, b0h, acc00); acc00 = MFMA16(a0h, b0l, acc00);
    acc01 = MFMA16(a0h, b1h, acc01); acc01 = MFMA16(a0l, b1h, acc01); acc01 = MFMA16(a0h, b1l, acc01);
    acc10 = MFMA16(a1h, b0h, acc10); acc10 = MFMA16(a1l, b0h, acc10); acc10 = MFMA16(a1h, b0l, acc10);
    acc11 = MFMA16(a1h, b1h, acc11); acc11 = MFMA16(a1l, b1h, acc11); acc11 = MFMA16(a1h, b1l, acc11);
  }
  __syncthreads();   // all frag reads of A/B done

  // ---- P6: write M over A region (bf16 hi/lo, kperm over its K=feat cols);
  //          restage W^T over B region. (C/D: col=lane&15, row=(lane>>4)*4+reg)
  {
#pragma unroll
    for (int mt = 0; mt < 2; ++mt)
#pragma unroll
      for (int nt = 0; nt < 2; ++nt)
#pragma unroll
        for (int r2 = 0; r2 < 4; ++r2) {
          f32x4 a = (mt == 0) ? (nt == 0 ? acc00 : acc01)
                              : (nt == 0 ? acc10 : acc11);
          float f = a[r2];
          int row = (mg << 5) + (mt << 4) + ((lane >> 4) << 2) + r2;
          int col = (ng << 5) + (nt << 4) + (lane & 15);
          unsigned hi = f2bf(f);
          unsigned lo = f2bf(f - bf2f(hi));
          int byte = swzb(row, kperm(col) << 1);
          *(unsigned short*)(sm + byte) = (unsigned short)hi;
          *(unsigned short*)(sm + OFF_ALO + byte) = (unsigned short)lo;
        }
    const float* __restrict__ Wv = v ? W2 : W1;
    for (int idx = tid; idx < FEAT * HID; idx += 1024) {
      int k = idx >> 7, c = idx & 127;
      float f = Wv[idx];
      unsigned hi = f2bf(f);
      unsigned lo = f2bf(f - bf2f(hi));
      int byte = swzb(c, kperm(k) << 1);
      *(unsigned short*)(sm + OFF_BHI + byte) = (unsigned short)hi;
      *(unsigned short*)(sm + OFF_BLO + byte) = (unsigned short)lo;
      // k=115..127 pad: M[.][115..127] == 0 (X^T pad rows), products vanish.
    }
  }
  __syncthreads();

  // ---- P7: out = M @ W + b (bf16x3), acc init = bias
  {
    const float* __restrict__ bv = v ? b2 : b1;
    float bb0 = bv[(ng << 5) + (lane & 15)];
    float bb1 = bv[(ng << 5) + 16 + (lane & 15)];
    acc00 = splat4(bb0); acc01 = splat4(bb1);
    acc10 = splat4(bb0); acc11 = splat4(bb1);
  }
#pragma unroll
  for (int kc = 0; kc < 4; ++kc) {
    const int ko = (kc << 6) + kb;
    short8 a0h = *(const short8*)(sm + swzb(rA0, ko));
    short8 a0l = *(const short8*)(sm + OFF_ALO + swzb(rA0, ko));
    short8 a1h = *(const short8*)(sm + swzb(rA1, ko));
    short8 a1l = *(const short8*)(sm + OFF_ALO + swzb(rA1, ko));
    short8 b0h = *(const short8*)(sm + OFF_BHI + swzb(rB0, ko));
    short8 b0l = *(const short8*)(sm + OFF_BLO + swzb(rB0, ko));
    short8 b1h = *(const short8*)(sm + OFF_BHI + swzb(rB1, ko));
    short8 b1l = *(const short8*)(sm + OFF_BLO + swzb(rB1, ko));
    acc00 = MFMA16(a0h, b0h, acc00); acc00 = MFMA16(a0l, b0h, acc00); acc00 = MFMA16(a0h, b0l, acc00);
    acc01 = MFMA16(a0h, b1h, acc01); acc01 = MFMA16(a0l, b1h, acc01); acc01 = MFMA16(a0h, b1l, acc01);
    acc10 = MFMA16(a1h, b0h, acc10); acc10 = MFMA16(a1l, b0h, acc10); acc10 = MFMA16(a1h, b0l, acc10);
    acc11 = MFMA16(a1h, b1h, acc11); acc11 = MFMA16(a1l, b1h, acc11); acc11 = MFMA16(a1h, b1l, acc11);
  }

  // ---- P8: channel max (over 128 hid cols) per node row
#pragma unroll
  for (int mt = 0; mt < 2; ++mt)
#pragma unroll
    for (int r2 = 0; r2 < 4; ++r2) {
      f32x4 aN0 = (mt == 0) ? acc00 : acc10;
      f32x4 aN1 = (mt == 0) ? acc01 : acc11;
      float m = fmaxf(aN0[r2], aN1[r2]);
      m = fmaxf(m, __shfl_xor(m, 1, 64));
      m = fmaxf(m, __shfl_xor(m, 2, 64));
      m = fmaxf(m, __shfl_xor(m, 4, 64));
      m = fmaxf(m, __shfl_xor(m, 8, 64));
      if ((lane & 15) == 0) {
        int row = (mg << 5) + (mt << 4) + ((lane >> 4) << 2) + r2;
        pmaxp[(ng << 7) + row] = m;
      }
    }
  __syncthreads();
  if (tid < NODES) {
    float m = fmaxf(fmaxf(pmaxp[tid], pmaxp[128 + tid]),
                    fmaxf(pmaxp[256 + tid], pmaxp[384 + tid]));
    featws[g * 232 + 2 * tid + v] = m;   // stack([x1,x2],1).reshape
  }
}

// ---------------- K2: MLP  relu(feat@W6+b6)@W7+b7 ----------------
// 1024 threads: col = tid&511, K-half = tid>>9 (116 rows each), LDS combine.
__global__ __launch_bounds__(1024) void k_mlp(
    const float* __restrict__ featws, const float* __restrict__ W6,
    const float* __restrict__ b6, const float* __restrict__ W7,
    const float* __restrict__ b7, float* __restrict__ out)
{
  __shared__ float sf[232];
  __shared__ float ph[512];
  __shared__ float red[8];
  const int g = blockIdx.x, tid = threadIdx.x;
  if (tid < 232) sf[tid] = featws[g * 232 + tid];
  __syncthreads();

  const int col = tid & 511, half = tid >> 9;
  const float* __restrict__ w6p = W6 + (size_t)(half * 116) * HC + col;
  const float* __restrict__ sfh = sf + half * 116;
  float p = 0.f;
#pragma unroll 4
  for (int k = 0; k < 116; ++k)
    p = fmaf(sfh[k], w6p[(size_t)k * HC], p);
  if (half) ph[col] = p;
  __syncthreads();

  if (!half) {
    float a = b6[col] + p + ph[col];
    a = fmaxf(a, 0.f) * W7[col];
#pragma unroll
    for (int off = 32; off >= 1; off >>= 1) a += __shfl_xor(a, off, 64);
    if ((tid & 63) == 0) red[tid >> 6] = a;
  }
  __syncthreads();
  if (tid == 0) {
    float t = b7[0];
#pragma unroll
    for (int i = 0; i < 8; ++i) t += red[i];
    out[g] = t;
  }
}

extern "C" void kernel_launch(void* const* d_in, const int* in_sizes, int n_in,
                              void* d_out, int out_size, void* d_ws, size_t ws_size,
                              hipStream_t stream)
{
  const float* x  = (const float*)d_in[0];
  const int*   ei = (const int*)d_in[1];
  const float* ew = (const float*)d_in[2];
  // d_in[3] = batch (unused by reference)
  const float* W1 = (const float*)d_in[4];
  const float* b1 = (const float*)d_in[5];
  const float* W2 = (const float*)d_in[6];
  const float* b2 = (const float*)d_in[7];
  const float* W6 = (const float*)d_in[8];
  const float* b6 = (const float*)d_in[9];
  const float* W7 = (const float*)d_in[10];
  const float* b7 = (const float*)d_in[11];

  float* featws = (float*)d_ws;                 // 256*232 f32 = 237 KB
  float* out    = (float*)d_out;

  hipLaunchKernelGGL(k_fused, dim3(2 * NB), dim3(1024), 0, stream,
                     x, ei, ew, W1, b1, W2, b2, featws);
  hipLaunchKernelGGL(k_mlp,   dim3(NB),     dim3(1024), 0, stream,
                     featws, W6, b6, W7, b7, out);
}